// Round 7
// baseline (951.466 us; speedup 1.0000x reference)
//
#include <hip/hip_runtime.h>
#include <hip/hip_bf16.h>

#define HID 64
#define FNODE 16
#define FEDGE 8
#define ZSTR 160  // bf16 elems per LDS row (136 data + pad to 5 ktiles)

typedef __bf16 v8bf __attribute__((ext_vector_type(8)));
typedef unsigned short us8 __attribute__((ext_vector_type(8)));
typedef float v4f __attribute__((ext_vector_type(4)));

// ---------------- packed split-bf16 weight fragments ----------------
__device__ __bf16 g_w1h[20480];
__device__ __bf16 g_w1l[20480];
__device__ __bf16 g_w2h[8192];
__device__ __bf16 g_w2l[8192];

__global__ void k_pack(const float* __restrict__ mW1, const float* __restrict__ mW2) {
    int gid = blockIdx.x * 256 + threadIdx.x;
    if (gid < 20480) {
        int j = gid & 7, lane = (gid >> 3) & 63, f = gid >> 9;
        int kt = f >> 3, nt = f & 7;
        int k = kt * 32 + (lane >> 4) * 8 + j;
        int col = nt * 16 + (lane & 15);
        float x = (k < 136) ? mW1[k * 128 + col] : 0.f;
        __bf16 hi = (__bf16)x;
        g_w1h[gid] = hi;
        g_w1l[gid] = (__bf16)(x - (float)hi);
    } else if (gid < 28672) {
        int t = gid - 20480;
        int j = t & 7, lane = (t >> 3) & 63, f = t >> 9;
        int kt = f >> 2, nt = f & 3;
        int k = kt * 32 + (lane >> 4) * 8 + j;
        int col = nt * 16 + (lane & 15);
        float x = mW2[k * 64 + col];
        __bf16 hi = (__bf16)x;
        g_w2h[t] = hi;
        g_w2l[t] = (__bf16)(x - (float)hi);
    }
}

// ---------------- CSR build (rp: counts -> starts -> cursor) ----------------
__global__ void k_count(const int* __restrict__ ei, int* __restrict__ rp, int E) {
    int e = blockIdx.x * 256 + threadIdx.x;
    if (e < E) atomicAdd(&rp[ei[E + e]], 1);
}

__global__ void k_disn(const int* __restrict__ rp, float* __restrict__ dis, int N) {
    int n = blockIdx.x * 256 + threadIdx.x;
    if (n < N) dis[n] = rsqrtf((float)(rp[n] + 1));  // +1 self-loop
}

__device__ __forceinline__ int block_scan_excl(int v, int* wsum) {
    int lane = threadIdx.x & 63, wv = threadIdx.x >> 6;
    int inc = v;
#pragma unroll
    for (int d = 1; d < 64; d <<= 1) {
        int t = __shfl_up(inc, d, 64);
        if (lane >= d) inc += t;
    }
    if (lane == 63) wsum[wv] = inc;
    __syncthreads();
    int off = 0;
    for (int w = 0; w < wv; ++w) off += wsum[w];
    return off + inc - v;  // exclusive
}

__global__ void k_scan1(int* __restrict__ rp, int* __restrict__ bsum, int N) {
    __shared__ int ws[4];
    int i = blockIdx.x * 256 + threadIdx.x;
    int v = (i < N) ? rp[i] : 0;
    int excl = block_scan_excl(v, ws);
    if (i < N) rp[i] = excl;
    if (threadIdx.x == 255) bsum[blockIdx.x] = excl + v;
}

__global__ void k_scan2(int* __restrict__ bsum, int nb) {
    __shared__ int ws[4];
    int i = threadIdx.x;
    int v = (i < nb) ? bsum[i] : 0;
    int excl = block_scan_excl(v, ws);
    if (i < nb) bsum[i] = excl;
}

__global__ void k_scan3(int* __restrict__ rp, const int* __restrict__ bsum, int N) {
    int i = blockIdx.x * 256 + threadIdx.x;
    if (i < N) rp[i] += bsum[i >> 8];
}

// post-fill rp[d] == start(d+1): row d = [ (d? rp[d-1]:0), rp[d] )
__global__ void k_fill(const int* __restrict__ ei, int* __restrict__ rp,
                       int* __restrict__ ce, int* __restrict__ eid, int E) {
    int e = blockIdx.x * 256 + threadIdx.x;
    if (e < E) {
        int s = ei[e], d = ei[E + e];
        int pos = atomicAdd(&rp[d], 1);
        ce[pos] = s | (d << 16);
        eid[pos] = e;
    }
}

// ---------------- conv1 in x-space ----------------
__global__ void k_dx(const float* __restrict__ x, const float* __restrict__ dis,
                     float* __restrict__ dx, int NF) {
    int t = blockIdx.x * 256 + threadIdx.x;
    if (t < NF) dx[t] = x[t] * dis[t >> 4];
}

__global__ __launch_bounds__(256) void k_pull1x(const float* __restrict__ dx,
                                                const int* __restrict__ rp,
                                                const int* __restrict__ ce,
                                                const float* __restrict__ dis,
                                                float* __restrict__ u, int N) {
    int grp = threadIdx.x >> 4, dim = threadIdx.x & 15;
    int n = blockIdx.x * 16 + grp;
    if (n >= N) return;
    int beg = n ? rp[n - 1] : 0;
    int end = rp[n];
    float a0 = dx[(size_t)n * 16 + dim];  // self
    float a1 = 0.f, a2 = 0.f, a3 = 0.f, a4 = 0.f, a5 = 0.f, a6 = 0.f, a7 = 0.f;
    int j = beg;
    for (; j + 7 < end; j += 8) {
        a0 += dx[(size_t)(ce[j] & 0xffff) * 16 + dim];
        a1 += dx[(size_t)(ce[j + 1] & 0xffff) * 16 + dim];
        a2 += dx[(size_t)(ce[j + 2] & 0xffff) * 16 + dim];
        a3 += dx[(size_t)(ce[j + 3] & 0xffff) * 16 + dim];
        a4 += dx[(size_t)(ce[j + 4] & 0xffff) * 16 + dim];
        a5 += dx[(size_t)(ce[j + 5] & 0xffff) * 16 + dim];
        a6 += dx[(size_t)(ce[j + 6] & 0xffff) * 16 + dim];
        a7 += dx[(size_t)(ce[j + 7] & 0xffff) * 16 + dim];
    }
    for (; j < end; ++j) a0 += dx[(size_t)(ce[j] & 0xffff) * 16 + dim];
    u[(size_t)n * 16 + dim] =
        dis[n] * (((a0 + a1) + (a2 + a3)) + ((a4 + a5) + (a6 + a7)));
}

// h1 = relu(u@W1+b1); y2 = dis*(h1@W2) -- fused per node
__global__ __launch_bounds__(256) void k_h1y2(const float* __restrict__ u,
                                              const float* __restrict__ W1,
                                              const float* __restrict__ b1,
                                              const float* __restrict__ W2,
                                              const float* __restrict__ dis,
                                              float* __restrict__ y2, int N) {
    __shared__ float sh[4][64];
    int wave = threadIdx.x >> 6, lane = threadIdx.x & 63;
    int n = blockIdx.x * 4 + wave;
    if (n >= N) return;
    float myu = u[(size_t)n * 16 + (lane & 15)];
    float h = b1[lane];
#pragma unroll
    for (int k = 0; k < 16; ++k)
        h = fmaf(__shfl(myu, k, 64), W1[k * HID + lane], h);
    h = fmaxf(h, 0.f);
    sh[wave][lane] = h;  // wave-synchronous
    float acc = 0.f;
#pragma unroll 8
    for (int k = 0; k < HID; ++k)
        acc = fmaf(sh[wave][k], W2[k * HID + lane], acc);
    y2[(size_t)n * HID + lane] = dis[n] * acc;
}

// h2 -> hi/lo bf16 planes hp[n][0..127]
__global__ __launch_bounds__(256) void k_pull2(const float* __restrict__ y,
                                               const int* __restrict__ rp,
                                               const int* __restrict__ ce,
                                               const float* __restrict__ dis,
                                               const float* __restrict__ b,
                                               __bf16* __restrict__ hp, int N) {
    int wave = threadIdx.x >> 6, lane = threadIdx.x & 63;
    int n = blockIdx.x * 4 + wave;
    if (n >= N) return;
    int beg = n ? rp[n - 1] : 0;
    int end = rp[n];
    float a0 = y[(size_t)n * HID + lane];  // self
    float a1 = 0.f, a2 = 0.f, a3 = 0.f, a4 = 0.f, a5 = 0.f, a6 = 0.f, a7 = 0.f;
    int j = beg;
    for (; j + 7 < end; j += 8) {
        a0 += y[(size_t)(ce[j] & 0xffff) * HID + lane];
        a1 += y[(size_t)(ce[j + 1] & 0xffff) * HID + lane];
        a2 += y[(size_t)(ce[j + 2] & 0xffff) * HID + lane];
        a3 += y[(size_t)(ce[j + 3] & 0xffff) * HID + lane];
        a4 += y[(size_t)(ce[j + 4] & 0xffff) * HID + lane];
        a5 += y[(size_t)(ce[j + 5] & 0xffff) * HID + lane];
        a6 += y[(size_t)(ce[j + 6] & 0xffff) * HID + lane];
        a7 += y[(size_t)(ce[j + 7] & 0xffff) * HID + lane];
    }
    for (; j < end; ++j) a0 += y[(size_t)(ce[j] & 0xffff) * HID + lane];
    float v = fmaxf(
        dis[n] * (((a0 + a1) + (a2 + a3)) + ((a4 + a5) + (a6 + a7))) + b[lane], 0.f);
    __bf16 hi = (__bf16)v;
    __bf16* p = hp + (size_t)n * 128;
    p[lane] = hi;
    p[64 + lane] = (__bf16)(v - (float)hi);
}

// ---------------- edge MLP: persistent blocks + reg double-buffered staging ----
struct ETile {  // per-thread staged fragment of one 64-edge tile
    us8 s0, s1, s2, s3;  // src chunks qt*4+0..3 (of 16: 0-7 hi, 8-15 lo)
    us8 d0, d1, d2, d3;  // dst chunks
    float4 ea;           // qt<2: ea elems qt*4..qt*4+3
};

__global__ __launch_bounds__(256, 4) void k_edge_mlp(
    const __bf16* __restrict__ hp, const int* __restrict__ ce,
    const int* __restrict__ eid, const float* __restrict__ ea,
    const float* __restrict__ mb1, const float* __restrict__ mb2,
    const float* __restrict__ mW3, const float* __restrict__ mb3,
    float* __restrict__ q, int E, int nTiles) {
    __shared__ __align__(16) __bf16 zh[64][ZSTR];
    __shared__ __align__(16) __bf16 zl[64][ZSTR];

    const int tid = threadIdx.x;
    const int lane = tid & 63;
    const int wave = tid >> 6;
    const int g = lane >> 4;
    const int cb = lane & 15;
    const int m = tid >> 2, qt = tid & 3;  // staging role: 4 threads per edge row
    const int stride = gridDim.x;

    const v8bf* w1h = (const v8bf*)g_w1h;
    const v8bf* w1l = (const v8bf*)g_w1l;
    const v8bf* w2h = (const v8bf*)g_w2h;
    const v8bf* w2l = (const v8bf*)g_w2l;
    const int nt0 = wave * 2;

    auto prefetch = [&](int t, ETile& T) {
        int p = t * 64 + m;
        bool valid = p < E;
        int cep = valid ? ce[p] : 0;
        int s = cep & 0xffff;
        int d = ((unsigned)cep) >> 16;
        const us8* S = (const us8*)(hp + (size_t)s * 128) + qt * 4;
        const us8* D = (const us8*)(hp + (size_t)d * 128) + qt * 4;
        T.s0 = S[0]; T.s1 = S[1]; T.s2 = S[2]; T.s3 = S[3];
        T.d0 = D[0]; T.d1 = D[1]; T.d2 = D[2]; T.d3 = D[3];
        if (qt < 2) {
            if (valid) {
                int e = eid[p];
                T.ea = *(const float4*)(ea + (size_t)e * FEDGE + qt * 4);
            } else {
                T.ea = (float4){0.f, 0.f, 0.f, 0.f};
            }
        }
    };

    auto stage = [&](const ETile& T) {
#define PUTC(cc, VS, VD)                                     \
    {                                                        \
        int c = qt * 4 + cc;                                 \
        __bf16* dst = (c < 8) ? &zh[m][0] : &zl[m][0];       \
        int base = (c & 7) * 8;                              \
        *(us8*)&dst[base] = VS;                              \
        *(us8*)&dst[64 + base] = VD;                         \
    }
        PUTC(0, T.s0, T.d0)
        PUTC(1, T.s1, T.d1)
        PUTC(2, T.s2, T.d2)
        PUTC(3, T.s3, T.d3)
#undef PUTC
        if (qt < 2) {
            int base = 128 + qt * 4;
#define PUTEA(i, V)                                  \
    {                                                \
        __bf16 hiv = (__bf16)(V);                    \
        zh[m][base + i] = hiv;                       \
        zl[m][base + i] = (__bf16)((V) - (float)hiv);\
    }
            PUTEA(0, T.ea.x) PUTEA(1, T.ea.y) PUTEA(2, T.ea.z) PUTEA(3, T.ea.w)
#undef PUTEA
        } else {
            __bf16* dst = (qt == 2) ? &zh[m][136] : &zl[m][136];
            us8 zz = {};
            *(us8*)&dst[0] = zz;
            *(us8*)&dst[8] = zz;
            *(us8*)&dst[16] = zz;
        }
    };

    ETile A, B;
    int t = blockIdx.x;
    if (t < nTiles) prefetch(t, A);

    for (; t < nTiles; t += stride) {
        __syncthreads();  // previous iteration fully done with LDS
        stage(A);
        int tn = t + stride;
        if (tn < nTiles) prefetch(tn, B);  // in-flight across the compute phase
        __syncthreads();

        // ---- layer 1: wave owns col-tiles nt0, nt0+1
        v4f acc[2][4];
        {
            float b0 = mb1[nt0 * 16 + cb];
            float b1v = mb1[nt0 * 16 + 16 + cb];
#pragma unroll
            for (int mt = 0; mt < 4; ++mt) {
                acc[0][mt] = (v4f){b0, b0, b0, b0};
                acc[1][mt] = (v4f){b1v, b1v, b1v, b1v};
            }
        }
#pragma unroll
        for (int kt = 0; kt < 5; ++kt) {
            v8bf bh0 = w1h[(kt * 8 + nt0) * 64 + lane];
            v8bf bl0 = w1l[(kt * 8 + nt0) * 64 + lane];
            v8bf bh1 = w1h[(kt * 8 + nt0 + 1) * 64 + lane];
            v8bf bl1 = w1l[(kt * 8 + nt0 + 1) * 64 + lane];
#pragma unroll
            for (int mt = 0; mt < 4; ++mt) {
                v8bf ah = *(const v8bf*)&zh[mt * 16 + cb][kt * 32 + g * 8];
                v8bf al = *(const v8bf*)&zl[mt * 16 + cb][kt * 32 + g * 8];
                acc[0][mt] = __builtin_amdgcn_mfma_f32_16x16x32_bf16(ah, bh0, acc[0][mt], 0, 0, 0);
                acc[0][mt] = __builtin_amdgcn_mfma_f32_16x16x32_bf16(ah, bl0, acc[0][mt], 0, 0, 0);
                acc[0][mt] = __builtin_amdgcn_mfma_f32_16x16x32_bf16(al, bh0, acc[0][mt], 0, 0, 0);
                acc[1][mt] = __builtin_amdgcn_mfma_f32_16x16x32_bf16(ah, bh1, acc[1][mt], 0, 0, 0);
                acc[1][mt] = __builtin_amdgcn_mfma_f32_16x16x32_bf16(ah, bl1, acc[1][mt], 0, 0, 0);
                acc[1][mt] = __builtin_amdgcn_mfma_f32_16x16x32_bf16(al, bh1, acc[1][mt], 0, 0, 0);
            }
        }
        __syncthreads();

        // ---- z1 = relu(acc) -> cols [nt0*16, nt0*16+32); D: col=lane&15, row=(lane>>4)*4+reg
#pragma unroll
        for (int c = 0; c < 2; ++c)
#pragma unroll
            for (int mt = 0; mt < 4; ++mt)
#pragma unroll
                for (int r = 0; r < 4; ++r) {
                    float vv = fmaxf(acc[c][mt][r], 0.f);
                    __bf16 hi = (__bf16)vv;
                    int row = mt * 16 + g * 4 + r;
                    int colx = (nt0 + c) * 16 + cb;
                    zh[row][colx] = hi;
                    zl[row][colx] = (__bf16)(vv - (float)hi);
                }
        __syncthreads();

        // ---- layer 2: wave owns col-tile nt=wave
        v4f acc2[4];
        {
            float b = mb2[wave * 16 + cb];
#pragma unroll
            for (int mt = 0; mt < 4; ++mt) acc2[mt] = (v4f){b, b, b, b};
        }
#pragma unroll
        for (int kt = 0; kt < 4; ++kt) {
            v8bf bh = w2h[(kt * 4 + wave) * 64 + lane];
            v8bf bl = w2l[(kt * 4 + wave) * 64 + lane];
#pragma unroll
            for (int mt = 0; mt < 4; ++mt) {
                v8bf ah = *(const v8bf*)&zh[mt * 16 + cb][kt * 32 + g * 8];
                v8bf al = *(const v8bf*)&zl[mt * 16 + cb][kt * 32 + g * 8];
                acc2[mt] = __builtin_amdgcn_mfma_f32_16x16x32_bf16(ah, bh, acc2[mt], 0, 0, 0);
                acc2[mt] = __builtin_amdgcn_mfma_f32_16x16x32_bf16(ah, bl, acc2[mt], 0, 0, 0);
                acc2[mt] = __builtin_amdgcn_mfma_f32_16x16x32_bf16(al, bh, acc2[mt], 0, 0, 0);
            }
        }
        __syncthreads();  // z reads done -> overlay qpart on zh

        // ---- layer 3: shfl-reduce 16 cols per wave, cross-wave via LDS
        float* qp = (float*)&zh[0][0];  // [4][64] overlay
        const float w3 = mW3[wave * 16 + cb];
#pragma unroll
        for (int mt = 0; mt < 4; ++mt) {
#pragma unroll
            for (int r = 0; r < 4; ++r) {
                float pr = fmaxf(acc2[mt][r], 0.f) * w3;
                pr += __shfl_xor(pr, 1, 16);
                pr += __shfl_xor(pr, 2, 16);
                pr += __shfl_xor(pr, 4, 16);
                pr += __shfl_xor(pr, 8, 16);
                if (cb == 0) qp[wave * 64 + mt * 16 + g * 4 + r] = pr;
            }
        }
        __syncthreads();
        if (tid < 64) {
            int p = t * 64 + tid;
            if (p < E)
                q[eid[p]] =
                    qp[tid] + qp[64 + tid] + qp[128 + tid] + qp[192 + tid] + mb3[0];
        }
        A = B;  // reg ping-pong (static struct copy)
    }
}

extern "C" void kernel_launch(void* const* d_in, const int* in_sizes, int n_in,
                              void* d_out, int out_size, void* d_ws, size_t ws_size,
                              hipStream_t stream) {
    const float* x   = (const float*)d_in[0];
    const int*   ei  = (const int*)d_in[1];
    const float* ea  = (const float*)d_in[2];
    const float* W1  = (const float*)d_in[3];
    const float* b1  = (const float*)d_in[4];
    const float* W2  = (const float*)d_in[5];
    const float* b2  = (const float*)d_in[6];
    const float* mW1 = (const float*)d_in[7];
    const float* mb1 = (const float*)d_in[8];
    const float* mW2 = (const float*)d_in[9];
    const float* mb2 = (const float*)d_in[10];
    const float* mW3 = (const float*)d_in[11];
    const float* mb3 = (const float*)d_in[12];
    float* q = (float*)d_out;

    const int N = in_sizes[0] / FNODE;
    const int E = in_sizes[1] / 2;

    // workspace layout (float units)
    float* dis = (float*)d_ws;                        // N (padded, +bsum tail)
    int* bsum  = (int*)(dis + 50000);                 // 256 (in dis pad)
    float* y2  = dis + ((N + 511) & ~255);            // N*HID
    float* hpf = y2 + (size_t)N * HID;                // N*128 bf16 == N*64 floats
    float* dx  = hpf;                                 // N*16 (overlay, dead pre-pull2)
    float* u   = hpf + (size_t)N * 16;                // N*16 (overlay, dead pre-pull2)
    int* rp    = (int*)(hpf + (size_t)N * HID);       // N
    int* ce    = rp + ((N + 255) & ~255);             // E
    int* eid   = ce + E;                              // E

    const int nT = 256;
    const int gN    = (N + nT - 1) / nT;
    const int gE    = (E + nT - 1) / nT;
    const int gNF   = (N * FNODE + nT - 1) / nT;
    const int g16   = (N + 15) / 16;
    const int gNode = (N + 3) / 4;
    const int nTiles = (E + 63) / 64;

    // pack split-bf16 weight fragments
    k_pack<<<112, nT, 0, stream>>>(mW1, mW2);

    // CSR build (by dst) + dis
    hipMemsetAsync(rp, 0, (size_t)N * sizeof(int), stream);
    k_count<<<gE, nT, 0, stream>>>(ei, rp, E);
    k_disn<<<gN, nT, 0, stream>>>(rp, dis, N);
    k_scan1<<<gN, nT, 0, stream>>>(rp, bsum, N);
    k_scan2<<<1, nT, 0, stream>>>(bsum, gN);
    k_scan3<<<gN, nT, 0, stream>>>(rp, bsum, N);
    k_fill<<<gE, nT, 0, stream>>>(ei, rp, ce, eid, E);

    // conv 1 in x-space, then fused h1+y2 projection
    k_dx<<<gNF, nT, 0, stream>>>(x, dis, dx, N * FNODE);
    k_pull1x<<<g16, nT, 0, stream>>>(dx, rp, ce, dis, u, N);
    k_h1y2<<<gNode, nT, 0, stream>>>(u, W1, b1, W2, dis, y2, N);

    // conv 2: pull y2, emit h2 as hi/lo bf16 planes
    k_pull2<<<gNode, nT, 0, stream>>>(y2, rp, ce, dis, b2, (__bf16*)hpf, N);

    // edge MLP: persistent, reg double-buffered staging (4 blocks/CU resident)
    k_edge_mlp<<<1024, nT, 0, stream>>>((const __bf16*)hpf, ce, eid, ea, mb1, mb2,
                                        mW3, mb3, q, E, nTiles);
}

// Round 8
// 713.554 us; speedup vs baseline: 1.3334x; 1.3334x over previous
//
#include <hip/hip_runtime.h>
#include <hip/hip_bf16.h>

#define HID 64
#define FNODE 16
#define FEDGE 8

typedef __bf16 v8bf __attribute__((ext_vector_type(8)));
typedef unsigned short us8 __attribute__((ext_vector_type(8)));
typedef float v4f __attribute__((ext_vector_type(4)));

// ---------------- packed split-bf16 weight fragments ----------------
__device__ __bf16 g_w1h[20480];
__device__ __bf16 g_w1l[20480];
__device__ __bf16 g_w2h[8192];
__device__ __bf16 g_w2l[8192];

__global__ void k_pack(const float* __restrict__ mW1, const float* __restrict__ mW2) {
    int gid = blockIdx.x * 256 + threadIdx.x;
    if (gid < 20480) {
        int j = gid & 7, lane = (gid >> 3) & 63, f = gid >> 9;
        int kt = f >> 3, nt = f & 7;
        int k = kt * 32 + (lane >> 4) * 8 + j;
        int col = nt * 16 + (lane & 15);
        float x = (k < 136) ? mW1[k * 128 + col] : 0.f;
        __bf16 hi = (__bf16)x;
        g_w1h[gid] = hi;
        g_w1l[gid] = (__bf16)(x - (float)hi);
    } else if (gid < 28672) {
        int t = gid - 20480;
        int j = t & 7, lane = (t >> 3) & 63, f = t >> 9;
        int kt = f >> 2, nt = f & 3;
        int k = kt * 32 + (lane >> 4) * 8 + j;
        int col = nt * 16 + (lane & 15);
        float x = mW2[k * 64 + col];
        __bf16 hi = (__bf16)x;
        g_w2h[t] = hi;
        g_w2l[t] = (__bf16)(x - (float)hi);
    }
}

// ---------------- CSR build (rp: counts -> starts -> cursor) ----------------
__global__ void k_count(const int* __restrict__ ei, int* __restrict__ rp, int E) {
    int e = blockIdx.x * 256 + threadIdx.x;
    if (e < E) atomicAdd(&rp[ei[E + e]], 1);
}

__global__ void k_disn(const int* __restrict__ rp, float* __restrict__ dis, int N) {
    int n = blockIdx.x * 256 + threadIdx.x;
    if (n < N) dis[n] = rsqrtf((float)(rp[n] + 1));  // +1 self-loop
}

__device__ __forceinline__ int block_scan_excl(int v, int* wsum) {
    int lane = threadIdx.x & 63, wv = threadIdx.x >> 6;
    int inc = v;
#pragma unroll
    for (int d = 1; d < 64; d <<= 1) {
        int t = __shfl_up(inc, d, 64);
        if (lane >= d) inc += t;
    }
    if (lane == 63) wsum[wv] = inc;
    __syncthreads();
    int off = 0;
    for (int w = 0; w < wv; ++w) off += wsum[w];
    return off + inc - v;  // exclusive
}

__global__ void k_scan1(int* __restrict__ rp, int* __restrict__ bsum, int N) {
    __shared__ int ws[4];
    int i = blockIdx.x * 256 + threadIdx.x;
    int v = (i < N) ? rp[i] : 0;
    int excl = block_scan_excl(v, ws);
    if (i < N) rp[i] = excl;
    if (threadIdx.x == 255) bsum[blockIdx.x] = excl + v;
}

__global__ void k_scan2(int* __restrict__ bsum, int nb) {
    __shared__ int ws[4];
    int i = threadIdx.x;
    int v = (i < nb) ? bsum[i] : 0;
    int excl = block_scan_excl(v, ws);
    if (i < nb) bsum[i] = excl;
}

__global__ void k_scan3(int* __restrict__ rp, const int* __restrict__ bsum, int N) {
    int i = blockIdx.x * 256 + threadIdx.x;
    if (i < N) rp[i] += bsum[i >> 8];
}

// post-fill rp[d] == start(d+1): row d = [ (d? rp[d-1]:0), rp[d] )
__global__ void k_fill(const int* __restrict__ ei, int* __restrict__ rp,
                       int* __restrict__ ce, int* __restrict__ eid, int E) {
    int e = blockIdx.x * 256 + threadIdx.x;
    if (e < E) {
        int s = ei[e], d = ei[E + e];
        int pos = atomicAdd(&rp[d], 1);
        ce[pos] = s | (d << 16);
        eid[pos] = e;
    }
}

// ---------------- conv1 in x-space ----------------
__global__ void k_dx(const float* __restrict__ x, const float* __restrict__ dis,
                     float* __restrict__ dx, int NF) {
    int t = blockIdx.x * 256 + threadIdx.x;
    if (t < NF) dx[t] = x[t] * dis[t >> 4];
}

__global__ __launch_bounds__(256) void k_pull1x(const float* __restrict__ dx,
                                                const int* __restrict__ rp,
                                                const int* __restrict__ ce,
                                                const float* __restrict__ dis,
                                                float* __restrict__ u, int N) {
    int grp = threadIdx.x >> 4, dim = threadIdx.x & 15;
    int n = blockIdx.x * 16 + grp;
    if (n >= N) return;
    int beg = n ? rp[n - 1] : 0;
    int end = rp[n];
    float a0 = dx[(size_t)n * 16 + dim];  // self
    float a1 = 0.f, a2 = 0.f, a3 = 0.f, a4 = 0.f, a5 = 0.f, a6 = 0.f, a7 = 0.f;
    int j = beg;
    for (; j + 7 < end; j += 8) {
        a0 += dx[(size_t)(ce[j] & 0xffff) * 16 + dim];
        a1 += dx[(size_t)(ce[j + 1] & 0xffff) * 16 + dim];
        a2 += dx[(size_t)(ce[j + 2] & 0xffff) * 16 + dim];
        a3 += dx[(size_t)(ce[j + 3] & 0xffff) * 16 + dim];
        a4 += dx[(size_t)(ce[j + 4] & 0xffff) * 16 + dim];
        a5 += dx[(size_t)(ce[j + 5] & 0xffff) * 16 + dim];
        a6 += dx[(size_t)(ce[j + 6] & 0xffff) * 16 + dim];
        a7 += dx[(size_t)(ce[j + 7] & 0xffff) * 16 + dim];
    }
    for (; j < end; ++j) a0 += dx[(size_t)(ce[j] & 0xffff) * 16 + dim];
    u[(size_t)n * 16 + dim] =
        dis[n] * (((a0 + a1) + (a2 + a3)) + ((a4 + a5) + (a6 + a7)));
}

// h1 = relu(u@W1+b1); y2 = dis*(h1@W2) -- fused per node
__global__ __launch_bounds__(256) void k_h1y2(const float* __restrict__ u,
                                              const float* __restrict__ W1,
                                              const float* __restrict__ b1,
                                              const float* __restrict__ W2,
                                              const float* __restrict__ dis,
                                              float* __restrict__ y2, int N) {
    __shared__ float sh[4][64];
    int wave = threadIdx.x >> 6, lane = threadIdx.x & 63;
    int n = blockIdx.x * 4 + wave;
    if (n >= N) return;
    float myu = u[(size_t)n * 16 + (lane & 15)];
    float h = b1[lane];
#pragma unroll
    for (int k = 0; k < 16; ++k)
        h = fmaf(__shfl(myu, k, 64), W1[k * HID + lane], h);
    h = fmaxf(h, 0.f);
    sh[wave][lane] = h;  // wave-synchronous
    float acc = 0.f;
#pragma unroll 8
    for (int k = 0; k < HID; ++k)
        acc = fmaf(sh[wave][k], W2[k * HID + lane], acc);
    y2[(size_t)n * HID + lane] = dis[n] * acc;
}

// h2 -> hi/lo bf16 planes hp[n][0..127]
__global__ __launch_bounds__(256) void k_pull2(const float* __restrict__ y,
                                               const int* __restrict__ rp,
                                               const int* __restrict__ ce,
                                               const float* __restrict__ dis,
                                               const float* __restrict__ b,
                                               __bf16* __restrict__ hp, int N) {
    int wave = threadIdx.x >> 6, lane = threadIdx.x & 63;
    int n = blockIdx.x * 4 + wave;
    if (n >= N) return;
    int beg = n ? rp[n - 1] : 0;
    int end = rp[n];
    float a0 = y[(size_t)n * HID + lane];  // self
    float a1 = 0.f, a2 = 0.f, a3 = 0.f, a4 = 0.f, a5 = 0.f, a6 = 0.f, a7 = 0.f;
    int j = beg;
    for (; j + 7 < end; j += 8) {
        a0 += y[(size_t)(ce[j] & 0xffff) * HID + lane];
        a1 += y[(size_t)(ce[j + 1] & 0xffff) * HID + lane];
        a2 += y[(size_t)(ce[j + 2] & 0xffff) * HID + lane];
        a3 += y[(size_t)(ce[j + 3] & 0xffff) * HID + lane];
        a4 += y[(size_t)(ce[j + 4] & 0xffff) * HID + lane];
        a5 += y[(size_t)(ce[j + 5] & 0xffff) * HID + lane];
        a6 += y[(size_t)(ce[j + 6] & 0xffff) * HID + lane];
        a7 += y[(size_t)(ce[j + 7] & 0xffff) * HID + lane];
    }
    for (; j < end; ++j) a0 += y[(size_t)(ce[j] & 0xffff) * HID + lane];
    float v = fmaxf(
        dis[n] * (((a0 + a1) + (a2 + a3)) + ((a4 + a5) + (a6 + a7))) + b[lane], 0.f);
    __bf16 hi = (__bf16)v;
    __bf16* p = hp + (size_t)n * 128;
    p[lane] = hi;
    p[64 + lane] = (__bf16)(v - (float)hi);
}

// ---------------- edge MLP: global_load_lds staging + chunk-layout LDS ------
// z chunk layout: chunk(m edge, ch 0..31) at bf16-elem offset
//   (m>>4)*4096 + (ch>>2)*512 + (m&15)*32 + (ch&3)*8
// ch 0-7 = src-hi, 8-15 = src-lo, 16-23 = dst-hi, 24-31 = dst-lo.
// Matches exactly what 8 global_load_lds(width=16) per wave write:
// wave w, instr i, lane L -> edge m=w*16+(L>>2), ch=i*4+(L&3),
// LDS = zc + w*4096 + i*512 + L*8 elems (wave-uniform base + lane*16B).
__device__ __forceinline__ int zoff(int m, int ch) {
    return ((m >> 4) << 12) + ((ch >> 2) << 9) + ((m & 15) << 5) + ((ch & 3) << 3);
}

__global__ __launch_bounds__(256) void k_edge_mlp(
    const __bf16* __restrict__ hp, const int* __restrict__ ce,
    const int* __restrict__ eid, const float* __restrict__ ea,
    const float* __restrict__ mb1, const float* __restrict__ mb2,
    const float* __restrict__ mW3, const float* __restrict__ mb3,
    float* __restrict__ q, int E) {
    __shared__ __align__(16) __bf16 zc[16384];   // 32 KB z planes (chunk layout)
    __shared__ __align__(16) __bf16 eh[64][32];  // 4 KB z-cols 128..159 hi
    __shared__ __align__(16) __bf16 el[64][32];  // 4 KB z-cols 128..159 lo

    const int tid = threadIdx.x;
    const int lane = tid & 63;
    const int wave = tid >> 6;
    const int g = lane >> 4;
    const int cb = lane & 15;
    const int m0 = blockIdx.x * 64;

    // ---- stage z planes: 8 global_load_lds per wave (no VGPR round-trip)
    {
        const int me = wave * 16 + (lane >> 2);  // edge within tile
        const int cl = lane & 3;
        const int p = m0 + me;
        const bool valid = p < E;
        const int cep = valid ? ce[p] : 0;
        const int s = cep & 0xffff;
        const int d = ((unsigned)cep) >> 16;
        const __bf16* Sp = hp + (size_t)s * 128 + cl * 8;
        const __bf16* Dp = hp + (size_t)d * 128 + cl * 8;
        __bf16* lb = zc + wave * 4096;
#pragma unroll
        for (int i = 0; i < 4; ++i)
            __builtin_amdgcn_global_load_lds(
                (const __attribute__((address_space(1))) unsigned int*)(Sp + i * 32),
                (__attribute__((address_space(3))) unsigned int*)(lb + i * 512),
                16, 0, 0);
#pragma unroll
        for (int i = 0; i < 4; ++i)
            __builtin_amdgcn_global_load_lds(
                (const __attribute__((address_space(1))) unsigned int*)(Dp + i * 32),
                (__attribute__((address_space(3))) unsigned int*)(lb + (4 + i) * 512),
                16, 0, 0);
    }
    // ---- stage ea (fp32 -> split bf16, small) + zero pad
    {
        const int m = tid >> 2, qt = tid & 3;
        const int p = m0 + m;
        const bool valid = p < E;
        if (qt < 2) {
            float4 v = {0.f, 0.f, 0.f, 0.f};
            if (valid) {
                int e = eid[p];
                v = *(const float4*)(ea + (size_t)e * FEDGE + qt * 4);
            }
            const float* vf = (const float*)&v;
#pragma unroll
            for (int i2 = 0; i2 < 4; ++i2) {
                float vv = vf[i2];
                __bf16 hiv = (__bf16)vv;
                eh[m][qt * 4 + i2] = hiv;
                el[m][qt * 4 + i2] = (__bf16)(vv - (float)hiv);
            }
        } else {
            us8 zz = {};
            __bf16* dstp = (qt == 2) ? &eh[m][8] : &el[m][8];
            *(us8*)&dstp[0] = zz;
            *(us8*)&dstp[8] = zz;
            *(us8*)&dstp[16] = zz;
        }
    }
    __syncthreads();  // drains vmcnt (DMA) + lgkmcnt (ea writes)

    // ---- layer 1: wave owns col-tiles nt0, nt0+1 (32 of 128 cols)
    const int nt0 = wave * 2;
    v4f acc[2][4];
    {
        float b0 = mb1[nt0 * 16 + cb];
        float b1v = mb1[nt0 * 16 + 16 + cb];
#pragma unroll
        for (int mt = 0; mt < 4; ++mt) {
            acc[0][mt] = (v4f){b0, b0, b0, b0};
            acc[1][mt] = (v4f){b1v, b1v, b1v, b1v};
        }
    }
    const v8bf* w1h = (const v8bf*)g_w1h;
    const v8bf* w1l = (const v8bf*)g_w1l;
    const v8bf* w2h = (const v8bf*)g_w2h;
    const v8bf* w2l = (const v8bf*)g_w2l;
#pragma unroll
    for (int kt = 0; kt < 5; ++kt) {
        v8bf bh0 = w1h[(kt * 8 + nt0) * 64 + lane];
        v8bf bl0 = w1l[(kt * 8 + nt0) * 64 + lane];
        v8bf bh1 = w1h[(kt * 8 + nt0 + 1) * 64 + lane];
        v8bf bl1 = w1l[(kt * 8 + nt0 + 1) * 64 + lane];
#pragma unroll
        for (int mt = 0; mt < 4; ++mt) {
            v8bf ah, al;
            if (kt < 4) {
                int ch = (kt < 2) ? kt * 4 + g : 16 + (kt - 2) * 4 + g;
                ah = *(const v8bf*)&zc[zoff(mt * 16 + cb, ch)];
                al = *(const v8bf*)&zc[zoff(mt * 16 + cb, ch + 8)];
            } else {
                ah = *(const v8bf*)&eh[mt * 16 + cb][g * 8];
                al = *(const v8bf*)&el[mt * 16 + cb][g * 8];
            }
            acc[0][mt] = __builtin_amdgcn_mfma_f32_16x16x32_bf16(ah, bh0, acc[0][mt], 0, 0, 0);
            acc[0][mt] = __builtin_amdgcn_mfma_f32_16x16x32_bf16(ah, bl0, acc[0][mt], 0, 0, 0);
            acc[0][mt] = __builtin_amdgcn_mfma_f32_16x16x32_bf16(al, bh0, acc[0][mt], 0, 0, 0);
            acc[1][mt] = __builtin_amdgcn_mfma_f32_16x16x32_bf16(ah, bh1, acc[1][mt], 0, 0, 0);
            acc[1][mt] = __builtin_amdgcn_mfma_f32_16x16x32_bf16(ah, bl1, acc[1][mt], 0, 0, 0);
            acc[1][mt] = __builtin_amdgcn_mfma_f32_16x16x32_bf16(al, bh1, acc[1][mt], 0, 0, 0);
        }
    }
    __syncthreads();  // everyone done reading z before overwriting with z1

    // ---- z1 = relu(acc) written back into chunk layout (cols 0..127)
    // D: col = lane&15, row = (lane>>4)*4 + reg (m89-verified)
#pragma unroll
    for (int c = 0; c < 2; ++c)
#pragma unroll
        for (int mt = 0; mt < 4; ++mt)
#pragma unroll
            for (int r = 0; r < 4; ++r) {
                float vv = fmaxf(acc[c][mt][r], 0.f);
                __bf16 hiv = (__bf16)vv;
                int row = mt * 16 + g * 4 + r;
                int col = (nt0 + c) * 16 + cb;
                int chh = (col < 64) ? (col >> 3) : (8 + (col >> 3));
                zc[zoff(row, chh) + (cb & 7)] = hiv;
                zc[zoff(row, chh + 8) + (cb & 7)] = (__bf16)(vv - (float)hiv);
            }
    __syncthreads();

    // ---- layer 2: wave owns col-tile nt=wave (16 of 64 cols)
    v4f acc2[4];
    {
        float b = mb2[wave * 16 + cb];
#pragma unroll
        for (int mt = 0; mt < 4; ++mt) acc2[mt] = (v4f){b, b, b, b};
    }
#pragma unroll
    for (int kt = 0; kt < 4; ++kt) {
        v8bf bh = w2h[(kt * 4 + wave) * 64 + lane];
        v8bf bl = w2l[(kt * 4 + wave) * 64 + lane];
        int ch = (kt < 2) ? kt * 4 + g : 16 + (kt - 2) * 4 + g;
#pragma unroll
        for (int mt = 0; mt < 4; ++mt) {
            v8bf ah = *(const v8bf*)&zc[zoff(mt * 16 + cb, ch)];
            v8bf al = *(const v8bf*)&zc[zoff(mt * 16 + cb, ch + 8)];
            acc2[mt] = __builtin_amdgcn_mfma_f32_16x16x32_bf16(ah, bh, acc2[mt], 0, 0, 0);
            acc2[mt] = __builtin_amdgcn_mfma_f32_16x16x32_bf16(ah, bl, acc2[mt], 0, 0, 0);
            acc2[mt] = __builtin_amdgcn_mfma_f32_16x16x32_bf16(al, bh, acc2[mt], 0, 0, 0);
        }
    }
    __syncthreads();  // z reads done -> overlay qpart on zc

    // ---- layer 3: shfl-reduce 16 cols per wave, cross-wave via LDS
    float* qp = (float*)&zc[0];  // [4][64] overlay
    const float w3 = mW3[wave * 16 + cb];
#pragma unroll
    for (int mt = 0; mt < 4; ++mt) {
#pragma unroll
        for (int r = 0; r < 4; ++r) {
            float pr = fmaxf(acc2[mt][r], 0.f) * w3;
            pr += __shfl_xor(pr, 1, 16);
            pr += __shfl_xor(pr, 2, 16);
            pr += __shfl_xor(pr, 4, 16);
            pr += __shfl_xor(pr, 8, 16);
            if (cb == 0) qp[wave * 64 + mt * 16 + g * 4 + r] = pr;
        }
    }
    __syncthreads();
    if (tid < 64) {
        int p = m0 + tid;
        if (p < E)
            q[eid[p]] =
                qp[tid] + qp[64 + tid] + qp[128 + tid] + qp[192 + tid] + mb3[0];
    }
}

extern "C" void kernel_launch(void* const* d_in, const int* in_sizes, int n_in,
                              void* d_out, int out_size, void* d_ws, size_t ws_size,
                              hipStream_t stream) {
    const float* x   = (const float*)d_in[0];
    const int*   ei  = (const int*)d_in[1];
    const float* ea  = (const float*)d_in[2];
    const float* W1  = (const float*)d_in[3];
    const float* b1  = (const float*)d_in[4];
    const float* W2  = (const float*)d_in[5];
    const float* b2  = (const float*)d_in[6];
    const float* mW1 = (const float*)d_in[7];
    const float* mb1 = (const float*)d_in[8];
    const float* mW2 = (const float*)d_in[9];
    const float* mb2 = (const float*)d_in[10];
    const float* mW3 = (const float*)d_in[11];
    const float* mb3 = (const float*)d_in[12];
    float* q = (float*)d_out;

    const int N = in_sizes[0] / FNODE;
    const int E = in_sizes[1] / 2;

    // workspace layout (float units)
    float* dis = (float*)d_ws;                        // N (padded, +bsum tail)
    int* bsum  = (int*)(dis + 50000);                 // 256 (in dis pad)
    float* y2  = dis + ((N + 511) & ~255);            // N*HID
    float* hpf = y2 + (size_t)N * HID;                // N*128 bf16 == N*64 floats
    float* dx  = hpf;                                 // N*16 (overlay, dead pre-pull2)
    float* u   = hpf + (size_t)N * 16;                // N*16 (overlay, dead pre-pull2)
    int* rp    = (int*)(hpf + (size_t)N * HID);       // N
    int* ce    = rp + ((N + 255) & ~255);             // E
    int* eid   = ce + E;                              // E

    const int nT = 256;
    const int gN    = (N + nT - 1) / nT;
    const int gE    = (E + nT - 1) / nT;
    const int gNF   = (N * FNODE + nT - 1) / nT;
    const int g16   = (N + 15) / 16;
    const int gNode = (N + 3) / 4;
    const int gMLP  = (E + 63) / 64;

    // pack split-bf16 weight fragments
    k_pack<<<112, nT, 0, stream>>>(mW1, mW2);

    // CSR build (by dst) + dis
    hipMemsetAsync(rp, 0, (size_t)N * sizeof(int), stream);
    k_count<<<gE, nT, 0, stream>>>(ei, rp, E);
    k_disn<<<gN, nT, 0, stream>>>(rp, dis, N);
    k_scan1<<<gN, nT, 0, stream>>>(rp, bsum, N);
    k_scan2<<<1, nT, 0, stream>>>(bsum, gN);
    k_scan3<<<gN, nT, 0, stream>>>(rp, bsum, N);
    k_fill<<<gE, nT, 0, stream>>>(ei, rp, ce, eid, E);

    // conv 1 in x-space, then fused h1+y2 projection
    k_dx<<<gNF, nT, 0, stream>>>(x, dis, dx, N * FNODE);
    k_pull1x<<<g16, nT, 0, stream>>>(dx, rp, ce, dis, u, N);
    k_h1y2<<<gNode, nT, 0, stream>>>(u, W1, b1, W2, dis, y2, N);

    // conv 2: pull y2, emit h2 as hi/lo bf16 planes
    k_pull2<<<gNode, nT, 0, stream>>>(y2, rp, ce, dis, b2, (__bf16*)hpf, N);

    // edge MLP (MFMA, global_load_lds staging, CSR-ordered)
    k_edge_mlp<<<gMLP, nT, 0, stream>>>((const __bf16*)hpf, ce, eid, ea, mb1, mb2,
                                        mW3, mb3, q, E);
}